// Round 5
// baseline (408.387 us; speedup 1.0000x reference)
//
#include <hip/hip_runtime.h>

#define LQ     22500
#define SPA_H  58
#define SPA_W  100
#define S_TOT  5800
#define NCAMS  6
#define CDIM   256

typedef __attribute__((ext_vector_type(8))) _Float16 half8;
typedef __attribute__((ext_vector_type(4))) _Float16 half4;
typedef __attribute__((ext_vector_type(4))) float f32x4;

// ---------------- conversion pass: f32 -> f16 for A matrices and weights ---
// ranges (elements): value 8908800 | query 5760000 | W_val 65536 |
// W_off 32768 | W_attn 16384 | W_out 65536   (total 14849024, all /4)
__global__ __launch_bounds__(256) void cvt_all(
    const float* __restrict__ value, const float* __restrict__ query,
    const float* __restrict__ W_val, const float* __restrict__ W_off,
    const float* __restrict__ W_attn, const float* __restrict__ W_out,
    _Float16* __restrict__ val16, _Float16* __restrict__ q16,
    _Float16* __restrict__ Wv, _Float16* __restrict__ Wcat,
    _Float16* __restrict__ Wo) {
  const long long e = ((long long)blockIdx.x * 256 + threadIdx.x) * 4;
  const float* src; _Float16* dst; long long off;
  if (e < 8908800)        { src = value;  dst = val16;        off = e; }
  else if (e < 14668800)  { src = query;  dst = q16;          off = e - 8908800; }
  else if (e < 14734336)  { src = W_val;  dst = Wv;           off = e - 14668800; }
  else if (e < 14767104)  { src = W_off;  dst = Wcat;         off = e - 14734336; }
  else if (e < 14783488)  { src = W_attn; dst = Wcat + 32768; off = e - 14767104; }
  else if (e < 14849024)  { src = W_out;  dst = Wo;           off = e - 14783488; }
  else return;
  f32x4 v = *(const f32x4*)(src + off);
  half4 o;
  o[0] = (_Float16)v.x; o[1] = (_Float16)v.y; o[2] = (_Float16)v.z; o[3] = (_Float16)v.w;
  *(half4*)(dst + off) = o;
}

// ---------------- GEMM body: C[Mx N] = A[M x 256] @ W[N x 256]^T + bias ----
// 64-row tile / block, 4 waves own disjoint col ranges, reg ping-pong K-loop.
// All strides hardcoded 256. OUT_MODE: 0=f32, 2=f16. INPLACE: barrier first.
template<int N, int OUT_MODE, bool INPLACE>
__device__ __forceinline__ void gemm_body(
    const _Float16* __restrict__ A, const _Float16* __restrict__ W,
    const float* __restrict__ bias, const float* __restrict__ bias2,
    void* __restrict__ Cv, int M, int rowbase) {
  constexpr int NT = N / 64;
  const int lane = threadIdx.x & 63;
  const int wave = threadIdx.x >> 6;
  const int m15  = lane & 15;
  const int quad = lane >> 4;
  const int colbase = wave * (N / 4);
  const int kq = quad * 8;

  const _Float16* ap[4];
#pragma unroll
  for (int rt = 0; rt < 4; ++rt) {
    int r = rowbase + rt * 16 + m15;
    r = r < M ? r : M - 1;
    ap[rt] = A + (size_t)r * 256 + kq;
  }
  const _Float16* wp[NT];
#pragma unroll
  for (int t = 0; t < NT; ++t)
    wp[t] = W + (size_t)(colbase + t * 16 + m15) * 256 + kq;

  f32x4 acc[4][NT];
#pragma unroll
  for (int rt = 0; rt < 4; ++rt)
#pragma unroll
    for (int t = 0; t < NT; ++t) acc[rt][t] = (f32x4){0.f, 0.f, 0.f, 0.f};

  half8 a0[4], b0[NT], a1[4], b1[NT];
#define LOADSET(aa, bb, KO) \
  { _Pragma("unroll") for (int rt = 0; rt < 4; ++rt) aa[rt] = *(const half8*)(ap[rt] + (KO)); \
    _Pragma("unroll") for (int t = 0; t < NT; ++t)  bb[t]  = *(const half8*)(wp[t] + (KO)); }
#define MFMASET(aa, bb) \
  { _Pragma("unroll") for (int t = 0; t < NT; ++t) \
      _Pragma("unroll") for (int rt = 0; rt < 4; ++rt) \
        acc[rt][t] = __builtin_amdgcn_mfma_f32_16x16x32_f16(aa[rt], bb[t], acc[rt][t], 0, 0, 0); }

  LOADSET(a0, b0, 0)
#pragma unroll 1
  for (int kk = 0; kk < 192; kk += 64) {
    LOADSET(a1, b1, kk + 32)
    MFMASET(a0, b0)
    LOADSET(a0, b0, kk + 64)
    MFMASET(a1, b1)
  }
  LOADSET(a1, b1, 224)
  MFMASET(a0, b0)
  MFMASET(a1, b1)
#undef LOADSET
#undef MFMASET

  if (INPLACE) __syncthreads();   // all A-reads of this block retired

#pragma unroll
  for (int rt = 0; rt < 4; ++rt) {
    const int orow = rowbase + rt * 16 + quad * 4;
#pragma unroll
    for (int t = 0; t < NT; ++t) {
      const int col = colbase + t * 16 + m15;
      const float bv = (N == 192 && col >= 128) ? bias2[col - 128] : bias[col];
#pragma unroll
      for (int i = 0; i < 4; ++i) {
        const int r = orow + i;
        if (r < M) {
          const float v = acc[rt][t][i] + bv;
          if (OUT_MODE == 0) ((float*)Cv)[(size_t)r * 256 + col] = v;
          else               ((_Float16*)Cv)[(size_t)r * 256 + col] = (_Float16)v;
        }
      }
    }
  }
}

// fused input GEMMs: blocks [0,544) value-proj, [544,896) query-proj
__global__ __launch_bounds__(256) void gemm_inputs(
    const _Float16* __restrict__ val16, const _Float16* __restrict__ q16,
    const _Float16* __restrict__ Wv, const _Float16* __restrict__ Wcat,
    const float* __restrict__ b_val, const float* __restrict__ b_off,
    const float* __restrict__ b_attn,
    _Float16* __restrict__ vp, _Float16* __restrict__ qproj) {
  const int b = blockIdx.x;
  if (b < 544) gemm_body<256, 2, true>(val16, Wv, b_val, b_val, vp, 34800, b * 64);
  else         gemm_body<192, 2, true>(q16, Wcat, b_off, b_attn, qproj, LQ, (b - 544) * 64);
}

__global__ __launch_bounds__(256) void gemm_out_k(
    const _Float16* __restrict__ slots, const _Float16* __restrict__ Wo,
    const float* __restrict__ b_out, float* __restrict__ out) {
  gemm_body<256, 0, false>(slots, Wo, b_out, b_out, out, LQ, blockIdx.x * 64);
}

// ---------------- sampler: 8 queries/block, lane = (query, 16 channels) ----
__global__ __launch_bounds__(128) void sampler(
    const _Float16* __restrict__ vp,     // (6, 5800, 256) f16
    const _Float16* __restrict__ qproj,  // (LQ, 256) f16: [off128, attn64, x]
    const float* __restrict__ ref,       // f32 (6, 1, LQ, 4, 2)
    const int* __restrict__ bev,         // int32 (6, 1, LQ, 4)
    _Float16* __restrict__ slots)        // (LQ, 256) f16 (aliases qproj)
{
  const int t  = threadIdx.x;
  const int ql = t >> 4;
  const int s  = t & 15;
  const int h  = s >> 1;
  const int q  = blockIdx.x * 8 + ql;
  const bool qok = q < LQ;

  __shared__ float s_off[8][8][17];  // [ql][h][p*2+c], padded
  __shared__ float s_w8[8][8][9];    // [ql][h][p], padded
  __shared__ float s_ref[8][48];     // [ql][cam*8 + z*2 + c]
  __shared__ int   s_vis[8][6];

  if (qok) {
    const _Float16* qp = qproj + (size_t)q * 256;
    // offsets: chunk s covers flat [s*8, s*8+8) of the 128 off values
    {
      half8 oc = *(const half8*)(qp + s * 8);
#pragma unroll
      for (int i = 0; i < 8; ++i) {
        const int f = s * 8 + i;
        s_off[ql][f >> 4][f & 15] =
            (float)oc[i] * ((f & 1) ? (1.f / 58.f) : (1.f / 100.f));
      }
    }
    if (s < 8) {  // softmax for head s
      half8 aw = *(const half8*)(qp + 128 + s * 8);
      float m = -1e30f;
#pragma unroll
      for (int p = 0; p < 8; ++p) m = fmaxf(m, (float)aw[p]);
      float e[8], ssum = 0.f;
#pragma unroll
      for (int p = 0; p < 8; ++p) { e[p] = __expf((float)aw[p] - m); ssum += e[p]; }
      const float inv = 1.f / ssum;
#pragma unroll
      for (int p = 0; p < 8; ++p) s_w8[ql][s][p] = e[p] * inv;
    }
    if (s < 12) {
      const int cam = s >> 1, hf = s & 1;
      f32x4 r = *(const f32x4*)(ref + ((size_t)cam * LQ + q) * 8 + hf * 4);
      *(f32x4*)&s_ref[ql][s * 4] = r;
    }
    if (s < 6) {
      int4 bm = *(const int4*)(bev + ((size_t)s * LQ + q) * 4);
      s_vis[ql][s] = (bm.x + bm.y + bm.z + bm.w) > 0 ? 1 : 0;
    }
  }
  __syncthreads();
  if (!qok) return;

  int cnt = 0;
#pragma unroll
  for (int c = 0; c < 6; ++c) cnt += s_vis[ql][c];
  const float invc = 1.f / (float)(cnt > 0 ? cnt : 1);

  float acc[16];
#pragma unroll
  for (int i = 0; i < 16; ++i) acc[i] = 0.f;

#pragma unroll 1
  for (int cam = 0; cam < NCAMS; ++cam) {
    if (!s_vis[ql][cam]) continue;
    const _Float16* vpc = vp + (size_t)cam * (S_TOT * CDIM) + s * 16;

#pragma unroll 1
    for (int pp = 0; pp < 4; ++pp) {
      half8 v[16];
      float w[8];
#pragma unroll
      for (int j = 0; j < 2; ++j) {
        const int p = pp * 2 + j;
        const int z = p & 3;
        const float x = (s_ref[ql][cam * 8 + z * 2 + 0] + s_off[ql][h][p * 2 + 0]) * 100.f - 0.5f;
        const float y = (s_ref[ql][cam * 8 + z * 2 + 1] + s_off[ql][h][p * 2 + 1]) * 58.f - 0.5f;
        const float x0f = floorf(x), y0f = floorf(y);
        const float fx = x - x0f, fy = y - y0f;
        const int x0 = (int)x0f, y0 = (int)y0f;
        const float vx0 = (x0 >= 0 && x0 < SPA_W) ? 1.f : 0.f;
        const float vx1 = (x0 >= -1 && x0 < SPA_W - 1) ? 1.f : 0.f;
        const float vy0 = (y0 >= 0 && y0 < SPA_H) ? 1.f : 0.f;
        const float vy1 = (y0 >= -1 && y0 < SPA_H - 1) ? 1.f : 0.f;
        const int xc0 = min(max(x0, 0), SPA_W - 1), xc1 = min(max(x0 + 1, 0), SPA_W - 1);
        const int yc0 = min(max(y0, 0), SPA_H - 1), yc1 = min(max(y0 + 1, 0), SPA_H - 1);
        const float wgt = s_w8[ql][h][p];
        const float wy0 = (1.f - fy) * wgt, wy1 = fy * wgt;
        w[j * 4 + 0] = wy0 * (1.f - fx) * vy0 * vx0;
        w[j * 4 + 1] = wy0 * fx * vy0 * vx1;
        w[j * 4 + 2] = wy1 * (1.f - fx) * vy1 * vx0;
        w[j * 4 + 3] = wy1 * fx * vy1 * vx1;
        const _Float16* t00 = vpc + (size_t)(yc0 * SPA_W + xc0) * CDIM;
        const _Float16* t01 = vpc + (size_t)(yc0 * SPA_W + xc1) * CDIM;
        const _Float16* t10 = vpc + (size_t)(yc1 * SPA_W + xc0) * CDIM;
        const _Float16* t11 = vpc + (size_t)(yc1 * SPA_W + xc1) * CDIM;
        v[j * 8 + 0] = *(const half8*)t00; v[j * 8 + 1] = *(const half8*)(t00 + 8);
        v[j * 8 + 2] = *(const half8*)t01; v[j * 8 + 3] = *(const half8*)(t01 + 8);
        v[j * 8 + 4] = *(const half8*)t10; v[j * 8 + 5] = *(const half8*)(t10 + 8);
        v[j * 8 + 6] = *(const half8*)t11; v[j * 8 + 7] = *(const half8*)(t11 + 8);
      }
#pragma unroll
      for (int j = 0; j < 2; ++j)
#pragma unroll
        for (int tap = 0; tap < 4; ++tap) {
          const float wk = w[j * 4 + tap];
#pragma unroll
          for (int i = 0; i < 8; ++i) {
            acc[i]     = fmaf(wk, (float)v[j * 8 + tap * 2][i],     acc[i]);
            acc[8 + i] = fmaf(wk, (float)v[j * 8 + tap * 2 + 1][i], acc[8 + i]);
          }
        }
    }
  }

  half8 o0, o1;
#pragma unroll
  for (int i = 0; i < 8; ++i) {
    o0[i] = (_Float16)(acc[i] * invc);
    o1[i] = (_Float16)(acc[8 + i] * invc);
  }
  _Float16* sp = slots + (size_t)q * 256 + s * 16;
  *(half8*)sp = o0;
  *(half8*)(sp + 8) = o1;
}

extern "C" void kernel_launch(void* const* d_in, const int* in_sizes, int n_in,
                              void* d_out, int out_size, void* d_ws, size_t ws_size,
                              hipStream_t stream) {
  const float* query  = (const float*)d_in[0];
  const float* refpts = (const float*)d_in[1];
  const int*   bev    = (const int*)d_in[2];
  const float* value  = (const float*)d_in[3];
  const float* W_off  = (const float*)d_in[4];
  const float* b_off  = (const float*)d_in[5];
  const float* W_attn = (const float*)d_in[6];
  const float* b_attn = (const float*)d_in[7];
  const float* W_val  = (const float*)d_in[8];
  const float* b_val  = (const float*)d_in[9];
  const float* W_out  = (const float*)d_in[10];
  const float* b_out  = (const float*)d_in[11];

  char* ws = (char*)d_ws;
  _Float16* val16 = (_Float16*)(ws + 0);          // 17,817,600 B (also vp)
  _Float16* q16   = (_Float16*)(ws + 17817600);   // 11,520,000 B (also qproj, slots)
  _Float16* Wv    = (_Float16*)(ws + 29337600);   //    131,072 B
  _Float16* Wcat  = (_Float16*)(ws + 29468672);   //     98,304 B
  _Float16* Wo    = (_Float16*)(ws + 29566976);   //    131,072 B -> end 29,698,048

  cvt_all<<<14501, 256, 0, stream>>>(value, query, W_val, W_off, W_attn, W_out,
                                     val16, q16, Wv, Wcat, Wo);

  // value-proj (in-place val16->vp) + query-proj (in-place q16->qproj)
  gemm_inputs<<<896, 256, 0, stream>>>(val16, q16, Wv, Wcat,
                                       b_val, b_off, b_attn, val16, q16);

  // sampler: reads vp + qproj, writes slots in-place over qproj rows
  sampler<<<(LQ + 7) / 8, 128, 0, stream>>>(val16, q16, refpts, bev, q16);

  // output projection: f16 slots -> f32 d_out
  gemm_out_k<<<(LQ + 63) / 64, 256, 0, stream>>>(q16, Wo, b_out, (float*)d_out);
}